// Round 1
// baseline (355.845 us; speedup 1.0000x reference)
//
#include <hip/hip_runtime.h>

// MeanPooling: B=64 segments, L=2048 tokens each, D=512 fp32 features.
// out[0:B*D]        = per-segment mean                  (64*512   = 32768 floats)
// out[B*D : B*D+N]  = attn weights, 1/len per token     (131072 floats)
//
// Memory-bound: 256 MiB read, ~0.64 MiB written. Floor ~43 us at 6.3 TB/s.

#define SEG_B 64
#define SEG_L 2048
#define DIM   512
#define NSPLIT 16
#define TOK_PER_SPLIT (SEG_L / NSPLIT)   // 128

__global__ __launch_bounds__(256)
void MeanPooling_40845138985511_kernel(const float* __restrict__ x,
                                       const int* __restrict__ lengths,
                                       float* __restrict__ out,    // [B*D], pre-zeroed
                                       float* __restrict__ attn) { // [N]
    const int blk = blockIdx.x;
    const int b   = blk >> 4;            // segment
    const int s   = blk & (NSPLIT - 1);  // token split within segment
    const int tid = threadIdx.x;
    const int fg  = tid & 127;           // float4 group within the 512-wide row
    const int ro  = tid >> 7;            // row offset: 0 or 1

    const float inv = 1.0f / (float)lengths[b];

    const int tok0 = b * SEG_L + s * TOK_PER_SPLIT;  // first global token of this block
    const float4* xr = (const float4*)x + (size_t)tok0 * (DIM / 4) + fg;

    // Each thread sums its float4 column over 64 of the 128 tokens in this slice.
    float4 acc = make_float4(0.f, 0.f, 0.f, 0.f);
#pragma unroll 4
    for (int r = ro; r < TOK_PER_SPLIT; r += 2) {
        float4 v = xr[(size_t)r * (DIM / 4)];
        acc.x += v.x; acc.y += v.y; acc.z += v.z; acc.w += v.w;
    }

    // Combine the two row-phases (tid and tid+128 share the same feature group).
    __shared__ float4 sm[128];
    if (tid >= 128) sm[fg] = acc;
    __syncthreads();
    if (tid < 128) {
        float4 o = sm[fg];
        acc.x = (acc.x + o.x) * inv;
        acc.y = (acc.y + o.y) * inv;
        acc.z = (acc.z + o.z) * inv;
        acc.w = (acc.w + o.w) * inv;
        float* dst = out + (size_t)b * DIM + fg * 4;
        atomicAdd(dst + 0, acc.x);
        atomicAdd(dst + 1, acc.y);
        atomicAdd(dst + 2, acc.z);
        atomicAdd(dst + 3, acc.w);
    }

    // Attention weights for this block's 128 tokens.
    if (tid < TOK_PER_SPLIT) {
        attn[tok0 + tid] = inv;
    }
}

extern "C" void kernel_launch(void* const* d_in, const int* in_sizes, int n_in,
                              void* d_out, int out_size, void* d_ws, size_t ws_size,
                              hipStream_t stream) {
    const float* x       = (const float*)d_in[0];
    const int*   lengths = (const int*)d_in[1];   // JAX default x64-off: int64 -> int32
    float* out  = (float*)d_out;
    float* attn = out + SEG_B * DIM;

    // Zero the mean-accumulator region (d_out is poisoned to 0xAA each launch).
    hipMemsetAsync(d_out, 0, SEG_B * DIM * sizeof(float), stream);

    MeanPooling_40845138985511_kernel<<<SEG_B * NSPLIT, 256, 0, stream>>>(
        x, lengths, out, attn);
}